// Round 13
// baseline (211.068 us; speedup 1.0000x reference)
//
#include <hip/hip_runtime.h>
#include <hip/hip_bf16.h>
#include <stdint.h>
#include <math.h>

typedef unsigned int uint_t;
typedef __attribute__((ext_vector_type(8))) short bf16x8;   // 8 bf16 (4 VGPRs)
typedef __attribute__((ext_vector_type(4))) float f32x4;

#define FEAT 2048
#define DSTRIDE 2052   // FEAT + HIDDEN
#define WARM 40
#define LCH 1
#define STEPS (WARM + LCH)
#define NN 8192
#define NSL 8          // K-slices for k_px split-K
#define KS 256         // K per slice (NSL*KS = FEAT)
#define MBLK 64        // rows per k_px block (4 waves x 16)
#define WSTR (KS + 8)  // LDS stride in shorts
#define TSTR 20        // transpose-tile stride in floats (16B-aligned rows, bank-spread)

__device__ __forceinline__ float sigm_f(float x) {
    return __builtin_amdgcn_rcpf(1.f + __expf(-x));
}
__device__ __forceinline__ float tanh_f(float x) {
    // 1 - 2/(e^2x + 1); rcp is ~1 ulp, fine at 1e-2 threshold
    return 1.f - 2.f * __builtin_amdgcn_rcpf(__expf(2.f * x) + 1.f);
}
// native RNE cast -> compiler emits v_cvt_pk_bf16_f32 for pairs (m240:
// casts are the fast path; inline-asm cvt_pk is slower). Bit-identical to
// the manual RNE used in R11 (both round-to-nearest-even).
__device__ __forceinline__ short bf16c(float x) {
    return __builtin_bit_cast(short, __float2bfloat16(x));
}

// ---------------------------------------------------------------------------
// K1 v10 (R12 resubmission — R12 run died "container failed twice" with no
// profile; kernel audited: per-wave LDS transpose tile is same-wave write/
// read around a uniform barrier, all indices bounded, no constructs that can
// hang. R8 precedent: identical resubmit disambiguates infra vs kernel.)
// v10 = v9 (R11: 210us total, ~22us k_px) + two fixes:
//   1. Coalesced epilogue: v9's D-write was 4 scattered scalar stores/lane
//      (wave store touches 16 rows x 16B = 64 discrete 4B elems). Now: per-
//      wave LDS transpose tile (16x16 f32, stride-20 padded, 1.25KB/wave),
//      then ONE float4 store/lane — wave writes contiguous 1KB.
//   2. Native __float2bfloat16 (packed cvt) replaces manual-int RNE
//      (~256 VALU/thread -> ~64). Same RNE bits -> px2 bit-identical.
// Structure recap: px2p[s][n][gq] = feat[n, s*256:(s+1)*256]·W[gq,·]; grid
// 8 slices x 128 mgroups, 4 waves x 16 rows; W-slice staged once as bf16
// (one barrier), 8 chained mfma_f32_16x16x32_bf16; C/D map HW-verified
// (m89): col=lane&15, row=(lane>>4)*4+reg. A/B share k-map (l>>4)*8+i.
// px2p = 4MB at d_out head after px2, consumed by k_red.
// ---------------------------------------------------------------------------
__global__ __launch_bounds__(256) void k_px(
    const float* __restrict__ feat,
    const float* __restrict__ Wf, const float* __restrict__ Wi,
    const float* __restrict__ Wg, const float* __restrict__ Wo,
    float* __restrict__ px2p)
{
    __shared__ short WT[16 * WSTR];      // bf16 W-slice, 16 gq x 256 k
    __shared__ float TT[4][16 * TSTR];   // per-wave transpose tiles
    const int t = threadIdx.x;
    const int slice = blockIdx.x >> 7;    // 0..7
    const int mg = blockIdx.x & 127;      // 0..127
    const int kb = slice * KS;
    const float* Ws[4] = {Wf, Wi, Wg, Wo};

    // stage W slice as bf16: 16 x 256 = 1024 float4-groups, 4 per thread
    for (int i4 = t; i4 < 1024; i4 += 256) {
        const int gq = i4 >> 6;
        const int jj = (i4 & 63) << 2;
        const float4 v = *(const float4*)(Ws[gq >> 2] + (gq & 3) * DSTRIDE + kb + jj);
        short4 h;
        h.x = bf16c(v.x); h.y = bf16c(v.y);
        h.z = bf16c(v.z); h.w = bf16c(v.w);
        *(short4*)(&WT[gq * WSTR + jj]) = h;
    }
    __syncthreads();

    const int wv = t >> 6, l = t & 63;
    const int row0 = mg * MBLK + wv * 16;
    const int m  = l & 15;       // A row within tile / B col (gq)
    const int kg = l >> 4;       // k-group 0..3
    const float* fp = feat + (size_t)(row0 + m) * FEAT + kb + kg * 8;
    const short* bp = &WT[m * WSTR + kg * 8];

    f32x4 acc = {0.f, 0.f, 0.f, 0.f};
#pragma unroll
    for (int ks = 0; ks < KS / 32; ++ks) {   // 8 chained MFMAs
        const float4 a0 = *(const float4*)(fp + ks * 32);
        const float4 a1 = *(const float4*)(fp + ks * 32 + 4);
        bf16x8 af;
        af[0] = bf16c(a0.x); af[1] = bf16c(a0.y);
        af[2] = bf16c(a0.z); af[3] = bf16c(a0.w);
        af[4] = bf16c(a1.x); af[5] = bf16c(a1.y);
        af[6] = bf16c(a1.z); af[7] = bf16c(a1.w);
        const bf16x8 bfr = *(const bf16x8*)(bp + ks * 32);
        acc = __builtin_amdgcn_mfma_f32_16x16x32_bf16(af, bfr, acc, 0, 0, 0);
    }

    // epilogue: LDS-transpose then coalesced float4 store.
    // D map: col = lane&15 (m), row = kg*4 + r  [HW-verified m89]
    float* tl = &TT[wv][0];
#pragma unroll
    for (int r = 0; r < 4; ++r)
        tl[(kg * 4 + r) * TSTR + m] = acc[r];
    __syncthreads();   // cheap; also orders the per-wave LDS tile
    const int rr_ = l >> 2;        // row 0..15 within wave tile
    const int c4  = (l & 3) * 4;   // float4 column offset
    const float4 ov = *(const float4*)&tl[rr_ * TSTR + c4];
    *(float4*)&px2p[((size_t)slice * NN + row0 + rr_) * 16 + c4] = ov;
}

// ---------------------------------------------------------------------------
// K1b: reduce 8 slice-partials + add (b + theta). 128 blocks x 256 threads;
// thread i handles float4 i: n = i>>2, gate g = i&3 (4 consecutive gq).
// Reads 4MB (L2-resident), writes px2 512KB. Deterministic fixed-order sum.
// ---------------------------------------------------------------------------
__global__ __launch_bounds__(256) void k_red(
    const float4* __restrict__ px2p,
    const float* __restrict__ bfp, const float* __restrict__ bip,
    const float* __restrict__ bgp, const float* __restrict__ bop,
    const float* __restrict__ thf, const float* __restrict__ thi,
    const float* __restrict__ thg, const float* __restrict__ tho,
    float4* __restrict__ px2)
{
    const int i = blockIdx.x * 256 + threadIdx.x;   // 0..32767
    float4 s = px2p[i];
#pragma unroll
    for (int sl = 1; sl < NSL; ++sl) {
        const float4 v = px2p[(size_t)sl * 32768 + i];
        s.x += v.x; s.y += v.y; s.z += v.z; s.w += v.w;
    }
    const int g = i & 3;
    const float* bs[4] = {bfp, bip, bgp, bop};
    const float* ts[4] = {thf, thi, thg, tho};
    const float4 b  = *(const float4*)(bs[g]);
    const float4 th = *(const float4*)(ts[g]);
    s.x += b.x + th.x; s.y += b.y + th.y;
    s.z += b.z + th.z; s.w += b.w + th.w;
    px2[i] = s;
}

// ---------------------------------------------------------------------------
// K2: per-row warmup replay (UNCHANGED). 8192 chunks of 1 row; 128 blocks x
// 64 threads -> 128 CUs. Rows n<40 bit-exact via the n<0 no-update guard;
// adversarial warmup bound 0.84^40 ~ 9.4e-4 << 1e-2. px2 prefetched one
// step ahead. qlayer(z,th) = [c1c2c3, c0c1, c0c1c2, c0c1c2c3],
// c_w = cos(z_w + th_w) (theta pre-added by k_red).
// hout = LAST 128 KB of d_out (rows 8176..8191).
// ---------------------------------------------------------------------------
__global__ __launch_bounds__(64) void k_scan(
    const float* __restrict__ Wf, const float* __restrict__ Wi,
    const float* __restrict__ Wg, const float* __restrict__ Wo,
    const float* __restrict__ px2, float* __restrict__ hout)
{
    const int c = blockIdx.x * 64 + threadIdx.x;    // output row id 0..8191
    float wh[4][4][4];           // [gate][q][j]  (wave-uniform -> SGPRs)
    {
        const float* Ws[4] = {Wf, Wi, Wg, Wo};
#pragma unroll
        for (int g = 0; g < 4; ++g)
#pragma unroll
            for (int q = 0; q < 4; ++q)
#pragma unroll
                for (int j = 0; j < 4; ++j)
                    wh[g][q][j] = Ws[g][q * DSTRIDE + FEAT + j];
    }
    float h[4] = {0.f, 0.f, 0.f, 0.f};
    float cc[4] = {0.f, 0.f, 0.f, 0.f};

    float4 PN0, PN1, PN2, PN3;
    {
        const int n0 = c * LCH - WARM;
        const int nc = n0 < 0 ? 0 : n0;
        const float* p = px2 + (size_t)nc * 16;
        PN0 = *(const float4*)(p + 0);
        PN1 = *(const float4*)(p + 4);
        PN2 = *(const float4*)(p + 8);
        PN3 = *(const float4*)(p + 12);
    }

    for (int s = 0; s < STEPS; ++s) {
        const int n = c * LCH + s - WARM;

        float4 PP[4];
        PP[0] = PN0; PP[1] = PN1; PP[2] = PN2; PP[3] = PN3;

        {   // issue next-step loads now; they retire under this step's math
            int n2 = n + 1;
            n2 = n2 < 0 ? 0 : n2;
            n2 = n2 > (NN - 1) ? (NN - 1) : n2;
            const float* p2 = px2 + (size_t)n2 * 16;
            PN0 = *(const float4*)(p2 + 0);
            PN1 = *(const float4*)(p2 + 4);
            PN2 = *(const float4*)(p2 + 8);
            PN3 = *(const float4*)(p2 + 12);
        }

        float act[4][4];
#pragma unroll
        for (int g = 0; g < 4; ++g) {
            float z0 = PP[g].x, z1 = PP[g].y, z2 = PP[g].z, z3 = PP[g].w;
#pragma unroll
            for (int j = 0; j < 4; ++j) {
                z0 = fmaf(h[j], wh[g][0][j], z0);
                z1 = fmaf(h[j], wh[g][1][j], z1);
                z2 = fmaf(h[j], wh[g][2][j], z2);
                z3 = fmaf(h[j], wh[g][3][j], z3);
            }
            const float c0 = __cosf(z0), c1 = __cosf(z1);
            const float c2 = __cosf(z2), c3 = __cosf(z3);
            const float m01 = c0 * c1, t23 = c2 * c3;
            const float y0 = c1 * t23, y1 = m01, y2 = m01 * c2, y3 = m01 * t23;
            if (g == 2) {
                act[g][0] = tanh_f(y0); act[g][1] = tanh_f(y1);
                act[g][2] = tanh_f(y2); act[g][3] = tanh_f(y3);
            } else {
                act[g][0] = sigm_f(y0); act[g][1] = sigm_f(y1);
                act[g][2] = sigm_f(y2); act[g][3] = sigm_f(y3);
            }
        }
        if (n >= 0) {
#pragma unroll
            for (int q = 0; q < 4; ++q) {
                const float cn = fmaf(act[0][q], cc[q], act[1][q] * act[2][q]);
                cc[q] = cn;
                h[q] = act[3][q] * tanh_f(cn);
            }
        }
        if (s >= WARM) {
            *(float4*)(hout + (size_t)n * 4) = make_float4(h[0], h[1], h[2], h[3]);
        }
    }
}

// ---------------------------------------------------------------------------
// K3a: rows 0..8175, 8 rows per block (1022 blocks). Wfin fragment (8 rows x
// 16B) loaded into registers ONCE and reused across all 8 n-rows.
// Never writes the hout region (rows 8176..8191). ~64MB write floor ~10.5us.
// ---------------------------------------------------------------------------
__global__ __launch_bounds__(256) void k_out_main(
    const float* __restrict__ hout,
    const float* __restrict__ Wfin, const float* __restrict__ bfin,
    float* __restrict__ out)
{
    const int n0 = blockIdx.x * 8;
    const int ko = threadIdx.x * 8;
    float4 w[8];
#pragma unroll
    for (int j = 0; j < 8; ++j)
        w[j] = *(const float4*)(Wfin + (size_t)(ko + j) * 4);
    const float4 b0 = *(const float4*)(bfin + ko);
    const float4 b1 = *(const float4*)(bfin + ko + 4);
    const float bb[8] = {b0.x, b0.y, b0.z, b0.w, b1.x, b1.y, b1.z, b1.w};

#pragma unroll
    for (int r = 0; r < 8; ++r) {
        const int n = n0 + r;
        const float4 h = *(const float4*)(hout + (size_t)n * 4);
        float o[8];
#pragma unroll
        for (int j = 0; j < 8; ++j) {
            float v = bb[j];
            v = fmaf(h.x, w[j].x, v); v = fmaf(h.y, w[j].y, v);
            v = fmaf(h.z, w[j].z, v); v = fmaf(h.w, w[j].w, v);
            o[j] = v;
        }
        float* dst = out + (size_t)n * 2048 + ko;
        *(float4*)(dst)     = make_float4(o[0], o[1], o[2], o[3]);
        *(float4*)(dst + 4) = make_float4(o[4], o[5], o[6], o[7]);
    }
}

// ---------------------------------------------------------------------------
// K3b: rows 8176..8191 (bytes hold hout). Stage 16 h-vectors in LDS, barrier,
// overwrite. 16 threads/row x 128 cols.
// ---------------------------------------------------------------------------
__global__ __launch_bounds__(256) void k_out_tail(
    const float* __restrict__ hout,
    const float* __restrict__ Wfin, const float* __restrict__ bfin,
    float* __restrict__ out)
{
    __shared__ float hs[16 * 4];
    const int t = threadIdx.x;
    if (t < 64) hs[t] = hout[(size_t)8176 * 4 + t];
    __syncthreads();
    const int r = t >> 4;
    const int n = 8176 + r;
    const int c0 = (t & 15) * 128;
    const float4 h = *(const float4*)(&hs[r * 4]);
    for (int j = 0; j < 128; j += 8) {
        const int ko = c0 + j;
        const float4 b0 = *(const float4*)(bfin + ko);
        const float4 b1 = *(const float4*)(bfin + ko + 4);
        const float bb[8] = {b0.x, b0.y, b0.z, b0.w, b1.x, b1.y, b1.z, b1.w};
        float o[8];
#pragma unroll
        for (int jj = 0; jj < 8; ++jj) {
            const float4 w = *(const float4*)(Wfin + (size_t)(ko + jj) * 4);
            float v = bb[jj];
            v = fmaf(h.x, w.x, v); v = fmaf(h.y, w.y, v);
            v = fmaf(h.z, w.z, v); v = fmaf(h.w, w.w, v);
            o[jj] = v;
        }
        float* dst = out + (size_t)n * 2048 + ko;
        *(float4*)(dst)     = make_float4(o[0], o[1], o[2], o[3]);
        *(float4*)(dst + 4) = make_float4(o[4], o[5], o[6], o[7]);
    }
}

__global__ __launch_bounds__(256) void k_sentinel(float* __restrict__ out) {
    const size_t i = (size_t)blockIdx.x * 256 + threadIdx.x;
    *(float4*)(out + i * 4) = make_float4(123.f, 123.f, 123.f, 123.f);
}

extern "C" void kernel_launch(void* const* d_in, const int* in_sizes, int n_in,
                              void* d_out, int out_size, void* d_ws, size_t ws_size,
                              hipStream_t stream)
{
    const float* feat = (const float*)d_in[0];
    const float* Wf   = (const float*)d_in[1];
    const float* bfp  = (const float*)d_in[2];
    const float* Wi   = (const float*)d_in[3];
    const float* bip  = (const float*)d_in[4];
    const float* Wg   = (const float*)d_in[5];
    const float* bgp  = (const float*)d_in[6];
    const float* Wo   = (const float*)d_in[7];
    const float* bop  = (const float*)d_in[8];
    const float* thf  = (const float*)d_in[9];
    const float* thi  = (const float*)d_in[10];
    const float* thg  = (const float*)d_in[11];
    const float* tho  = (const float*)d_in[12];
    const float* Wfin = (const float*)d_in[13];
    const float* bfin = (const float*)d_in[14];

    bool ok = (n_in == 15) &&
              in_sizes[0] == 8192 * 2048 &&
              in_sizes[1] == 8208 && in_sizes[3] == 8208 &&
              in_sizes[5] == 8208 && in_sizes[7] == 8208 &&
              in_sizes[2] == 4 && in_sizes[4] == 4 &&
              in_sizes[6] == 4 && in_sizes[8] == 4 &&
              in_sizes[9] == 4 && in_sizes[10] == 4 &&
              in_sizes[11] == 4 && in_sizes[12] == 4 &&
              in_sizes[13] == 8192 && in_sizes[14] == 2048 &&
              out_size == 8192 * 2048;
    if (!ok) {
        hipLaunchKernelGGL(k_sentinel, dim3(8192 * 2048 / 1024), dim3(256), 0,
                           stream, (float*)d_out);
        return;
    }

    // Zero-workspace layout in d_out (64 MB f32):
    //   px2  = head 512 KB (out rows 0..63)      — final pre-activations
    //   px2p = next 4 MB  (out rows 64..575)     — 8 slice partials
    //   hout = tail 128 KB (out rows 8176..8191) — scan output
    // Order: k_px -> k_red -> k_scan -> k_out_{main,tail}; all on `stream`.
    char* ob = (char*)d_out;
    float* px2  = (float*)ob;
    float* px2p = (float*)(ob + (size_t)512 * 1024);
    float* hout = (float*)(ob + (size_t)NN * 2048 * 4 - (size_t)NN * 16);
    float* out  = (float*)d_out;

    hipLaunchKernelGGL(k_px, dim3(NSL * 128), dim3(256), 0, stream,
                       feat, Wf, Wi, Wg, Wo, px2p);
    hipLaunchKernelGGL(k_red, dim3(128), dim3(256), 0, stream,
                       (const float4*)px2p, bfp, bip, bgp, bop,
                       thf, thi, thg, tho, (float4*)px2);
    hipLaunchKernelGGL(k_scan, dim3(128), dim3(64), 0, stream,
                       Wf, Wi, Wg, Wo, px2, hout);
    hipLaunchKernelGGL(k_out_main, dim3(1022), dim3(256), 0, stream,
                       hout, Wfin, bfin, out);
    hipLaunchKernelGGL(k_out_tail, dim3(1), dim3(256), 0, stream,
                       hout, Wfin, bfin, out);
}